// Round 7
// baseline (475.780 us; speedup 1.0000x reference)
//
#include <hip/hip_runtime.h>
#include <hip/hip_bf16.h>
#include <math.h>

#define N_NODES 100000
#define IN_F 256
#define HID 128
#define NCLS 40

typedef __attribute__((ext_vector_type(8))) short short8;
typedef __attribute__((ext_vector_type(4))) float f32x4;

__device__ __forceinline__ short f2bf(float f){
  union { float f; unsigned u; } x; x.f = f;
  unsigned r = (x.u + 0x7fffu + ((x.u >> 16) & 1u)) >> 16;
  return (short)r;
}
__device__ __forceinline__ float bf2f(unsigned short u){
  union { unsigned u; float f; } x; x.u = ((unsigned)u) << 16;
  return x.f;
}

// ---------------- CSR build ----------------
__global__ void k_zero(int* p, int n){
  int i = blockIdx.x*blockDim.x + threadIdx.x;
  if(i < n) p[i] = 0;
}

// XCD-colored count; NT loads keep the dst stream from evicting hot counts.
__global__ __launch_bounds__(256) void k_count(const int* __restrict__ dst,
                                               int* __restrict__ counts, int e){
  const int color = blockIdx.x & 7;
  const int lo = color * (N_NODES/8), hi = lo + (N_NODES/8);
  const int stride = (gridDim.x >> 3) * 256;
  for(int i = (blockIdx.x >> 3)*256 + threadIdx.x; i < e; i += stride){
    const int d = __builtin_nontemporal_load(dst + i);
    if(d >= lo && d < hi) atomicAdd(&counts[d], 1);
  }
}

#define SCAN_BLK 512
__global__ void k_scanA(const int* __restrict__ counts, int* __restrict__ offs,
                        int* __restrict__ partials, int n){
  __shared__ int s[SCAN_BLK];
  const int t = threadIdx.x;
  const int i = blockIdx.x*SCAN_BLK + t;
  int v = (i < n) ? counts[i] : 0;
  s[t] = v; __syncthreads();
  for(int d = 1; d < SCAN_BLK; d <<= 1){
    int add = (t >= d) ? s[t-d] : 0;
    __syncthreads();
    s[t] += add;
    __syncthreads();
  }
  if(i < n) offs[i] = s[t] - v;                 // block-local exclusive
  if(t == SCAN_BLK-1) partials[blockIdx.x] = s[t];
}

__global__ void k_scanB(int* partials, int n){
  __shared__ int s[256];
  const int t = threadIdx.x;
  int v = (t < n) ? partials[t] : 0;
  s[t] = v; __syncthreads();
  for(int d = 1; d < 256; d <<= 1){
    int add = (t >= d) ? s[t-d] : 0;
    __syncthreads();
    s[t] += add;
    __syncthreads();
  }
  if(t < n) partials[t] = s[t] - v;             // exclusive
}

__global__ void k_scanC(int* __restrict__ offs, const int* __restrict__ partials,
                        int* __restrict__ cursor, int n){
  int i = blockIdx.x*blockDim.x + threadIdx.x;
  if(i < n){
    int v = offs[i] + partials[blockIdx.x];
    offs[i] = v;
    cursor[i] = v;
  }
}

// XCD-colored scatter with NT streaming reads.
__global__ __launch_bounds__(256) void k_scatter(const int* __restrict__ src,
                                                 const int* __restrict__ dst,
                                                 int* __restrict__ cursor,
                                                 int* __restrict__ esrc, int e){
  const int color = blockIdx.x & 7;
  const int lo = color * (N_NODES/8), hi = lo + (N_NODES/8);
  const int stride = (gridDim.x >> 3) * 256;
  for(int i = (blockIdx.x >> 3)*256 + threadIdx.x; i < e; i += stride){
    const int d = __builtin_nontemporal_load(dst + i);
    if(d >= lo && d < hi){
      const int s = __builtin_nontemporal_load(src + i);
      int pos = atomicAdd(&cursor[d], 1);
      esrc[pos] = s;
    }
  }
}

// ---------------- pre GEMM: h0 = x @ W_pre + b_pre  (f32 in, bf16 out) ----------------
// 4 waves/block, grid 512 (2 blocks/CU = round-5 proven config), plus
// cross-tile ping-pong pipelining: tile t+1's 16 dwordx4 loads issue before
// tile t's convert/MFMA/store, hiding HBM latency under compute.
__global__ __launch_bounds__(256, 2) void k_gemm_pre(
    const float* __restrict__ x, const float* __restrict__ W,
    const float* __restrict__ b, unsigned short* __restrict__ out)
{
  __shared__ short wlds[8][8][64][8];   // [ct][kb][lane][j] : B-frag layout, 64 KiB
  const int t = threadIdx.x;
  for(int idx = t; idx < 8*8*64; idx += 256){
    const int ct = idx >> 9, kb = (idx >> 6) & 7, l = idx & 63;
    const int col = ct*16 + (l & 15);
    const int kbase = kb*32 + (l >> 4)*8;
    short8 v;
    #pragma unroll
    for(int j = 0; j < 8; j++) v[j] = f2bf(W[(size_t)(kbase+j)*HID + col]);
    *reinterpret_cast<short8*>(&wlds[ct][kb][l][0]) = v;
  }
  __syncthreads();
  const int wave = t >> 6, lane = t & 63;
  const int r_in = lane & 15, kg = lane >> 4;
  const int NT = N_NODES/16, stride = gridDim.x*4;

  auto loadx = [&](int tile, float4 (&xa)[8], float4 (&xb)[8]){
    const float* xp = x + (size_t)(tile*16 + r_in)*IN_F + kg*8;
    #pragma unroll
    for(int kb = 0; kb < 8; kb++){
      xa[kb] = *reinterpret_cast<const float4*>(xp + kb*32);
      xb[kb] = *reinterpret_cast<const float4*>(xp + kb*32 + 4);
    }
  };
  auto compute = [&](int tile, const float4 (&xa)[8], const float4 (&xb)[8]){
    f32x4 acc[8];
    #pragma unroll
    for(int ct = 0; ct < 8; ct++) acc[ct] = (f32x4){0.f,0.f,0.f,0.f};
    #pragma unroll
    for(int kb = 0; kb < 8; kb++){
      short8 a;
      a[0]=f2bf(xa[kb].x); a[1]=f2bf(xa[kb].y); a[2]=f2bf(xa[kb].z); a[3]=f2bf(xa[kb].w);
      a[4]=f2bf(xb[kb].x); a[5]=f2bf(xb[kb].y); a[6]=f2bf(xb[kb].z); a[7]=f2bf(xb[kb].w);
      #pragma unroll
      for(int ct = 0; ct < 8; ct++){
        short8 bb = *reinterpret_cast<const short8*>(&wlds[ct][kb][lane][0]);
        acc[ct] = __builtin_amdgcn_mfma_f32_16x16x32_bf16(a, bb, acc[ct], 0, 0, 0);
      }
    }
    const int row0 = tile*16;
    #pragma unroll
    for(int ct = 0; ct < 8; ct++){
      const int col = ct*16 + r_in;
      const float bias = b[col];
      #pragma unroll
      for(int i = 0; i < 4; i++)
        out[(size_t)(row0 + kg*4 + i)*HID + col] = (unsigned short)f2bf(acc[ct][i] + bias);
    }
  };

  int tile = blockIdx.x*4 + wave;
  if(tile >= NT) return;
  float4 xaA[8], xbA[8], xaB[8], xbB[8];
  loadx(tile, xaA, xbA);
  for(;;){
    int nt = tile + stride;
    bool more = nt < NT;
    if(more) loadx(nt, xaB, xbB);
    compute(tile, xaA, xbA);
    if(!more) break;
    tile = nt;
    nt = tile + stride;
    more = nt < NT;
    if(more) loadx(nt, xaA, xbA);
    compute(tile, xaB, xbB);
    if(!more) break;
    tile = nt;
  }
}

// ------- sage GEMM: out = relu(mean @ Wl + bl + h @ Wr)  (bf16 in/out) -------
// Same 4-wave / grid-512 config with cross-tile ping-pong pipelining.
__global__ __launch_bounds__(256, 2) void k_gemm_sage(
    const unsigned short* __restrict__ mean, const unsigned short* __restrict__ h,
    const float* __restrict__ Wl, const float* __restrict__ bl,
    const float* __restrict__ Wr, unsigned short* __restrict__ out)
{
  __shared__ short wlds[8][8][64][8];   // kb 0..3 -> Wl, 4..7 -> Wr
  const int t = threadIdx.x;
  for(int idx = t; idx < 8*8*64; idx += 256){
    const int ct = idx >> 9, kb = (idx >> 6) & 7, l = idx & 63;
    const float* Wsrc = (kb < 4) ? Wl : Wr;
    const int col = ct*16 + (l & 15);
    const int kbase = (kb & 3)*32 + (l >> 4)*8;
    short8 v;
    #pragma unroll
    for(int j = 0; j < 8; j++) v[j] = f2bf(Wsrc[(size_t)(kbase+j)*HID + col]);
    *reinterpret_cast<short8*>(&wlds[ct][kb][l][0]) = v;
  }
  __syncthreads();
  const int wave = t >> 6, lane = t & 63;
  const int r_in = lane & 15, kg = lane >> 4;
  const int NT = N_NODES/16, stride = gridDim.x*4;

  auto loadx = [&](int tile, short8 (&am)[4], short8 (&ah)[4]){
    const size_t base = (size_t)(tile*16 + r_in)*HID + kg*8;
    #pragma unroll
    for(int kb = 0; kb < 4; kb++){
      am[kb] = *reinterpret_cast<const short8*>(mean + base + kb*32);
      ah[kb] = *reinterpret_cast<const short8*>(h    + base + kb*32);
    }
  };
  auto compute = [&](int tile, const short8 (&am)[4], const short8 (&ah)[4]){
    f32x4 acc[8];
    #pragma unroll
    for(int ct = 0; ct < 8; ct++) acc[ct] = (f32x4){0.f,0.f,0.f,0.f};
    #pragma unroll
    for(int kb = 0; kb < 8; kb++){
      short8 a = (kb < 4) ? am[kb & 3] : ah[kb & 3];
      #pragma unroll
      for(int ct = 0; ct < 8; ct++){
        short8 bb = *reinterpret_cast<const short8*>(&wlds[ct][kb][lane][0]);
        acc[ct] = __builtin_amdgcn_mfma_f32_16x16x32_bf16(a, bb, acc[ct], 0, 0, 0);
      }
    }
    const int row0 = tile*16;
    #pragma unroll
    for(int ct = 0; ct < 8; ct++){
      const int col = ct*16 + r_in;
      const float bias = bl[col];
      #pragma unroll
      for(int i = 0; i < 4; i++){
        float v = fmaxf(acc[ct][i] + bias, 0.f);
        out[(size_t)(row0 + kg*4 + i)*HID + col] = (unsigned short)f2bf(v);
      }
    }
  };

  int tile = blockIdx.x*4 + wave;
  if(tile >= NT) return;
  short8 amA[4], ahA[4], amB[4], ahB[4];
  loadx(tile, amA, ahA);
  for(;;){
    int nt = tile + stride;
    bool more = nt < NT;
    if(more) loadx(nt, amB, ahB);
    compute(tile, amA, ahA);
    if(!more) break;
    tile = nt;
    nt = tile + stride;
    more = nt < NT;
    if(more) loadx(nt, amA, ahA);
    compute(tile, amB, ahB);
    if(!more) break;
    tile = nt;
  }
}

// ---------------- CSR mean aggregation (bf16 h -> bf16 mean) ----------------
__global__ __launch_bounds__(256) void k_aggregate(
    const unsigned short* __restrict__ h, const int* __restrict__ offs,
    const int* __restrict__ counts, const int* __restrict__ esrc,
    unsigned short* __restrict__ mean)
{
  const int node = blockIdx.x*4 + (threadIdx.x >> 6);
  const int lane = threadIdx.x & 63;
  if(node >= N_NODES) return;
  const int beg = offs[node];
  const int deg = counts[node];
  const unsigned* hp = (const unsigned*)h;
  float a0 = 0.f, a1 = 0.f;
  for(int base = 0; base < deg; base += 64){
    const int rem = deg - base;
    const int cnt = rem < 64 ? rem : 64;
    const int myi = (lane < cnt) ? esrc[beg + base + lane] : 0;   // coalesced
    int e = 0;
    for(; e + 8 <= cnt; e += 8){
      unsigned v[8];
      #pragma unroll
      for(int u = 0; u < 8; u++){
        const int s = __builtin_amdgcn_readlane(myi, e + u);
        v[u] = hp[(size_t)s*64 + lane];
      }
      #pragma unroll
      for(int u = 0; u < 8; u++){
        a0 += bf2f((unsigned short)(v[u] & 0xffffu));
        a1 += bf2f((unsigned short)(v[u] >> 16));
      }
    }
    for(; e < cnt; e++){
      const int s = __builtin_amdgcn_readlane(myi, e);
      const unsigned vv = hp[(size_t)s*64 + lane];
      a0 += bf2f((unsigned short)(vv & 0xffffu));
      a1 += bf2f((unsigned short)(vv >> 16));
    }
  }
  const float inv = (deg > 0) ? (1.0f/(float)deg) : 0.f;
  a0 *= inv; a1 *= inv;
  unsigned o = ((unsigned)(unsigned short)f2bf(a1) << 16) | (unsigned)(unsigned short)f2bf(a0);
  ((unsigned*)mean)[(size_t)node*64 + lane] = o;
}

// ---------------- post: log_softmax(h @ W_post + b_post), MFMA ----------------
__global__ __launch_bounds__(256) void k_post(
    const unsigned short* __restrict__ h, const float* __restrict__ W,
    const float* __restrict__ b, float* __restrict__ out)
{
  __shared__ short wlds[3][4][64][8];   // [ct][kb][lane][j], 12 KiB
  __shared__ float bias_s[48];
  const int t = threadIdx.x;
  for(int idx = t; idx < 3*4*64; idx += 256){
    const int ct = idx >> 8, kb = (idx >> 6) & 3, l = idx & 63;
    const int col = ct*16 + (l & 15);
    const int kbase = kb*32 + (l >> 4)*8;
    short8 v;
    #pragma unroll
    for(int j = 0; j < 8; j++)
      v[j] = (col < NCLS) ? f2bf(W[(size_t)(kbase+j)*NCLS + col]) : (short)0;
    *reinterpret_cast<short8*>(&wlds[ct][kb][l][0]) = v;
  }
  if(t < 48) bias_s[t] = (t < NCLS) ? b[t] : -1e30f;
  __syncthreads();
  const int wave = t >> 6, lane = t & 63;
  const int r_in = lane & 15, kg = lane >> 4;
  for(int tile = blockIdx.x*4 + wave; tile < N_NODES/16; tile += gridDim.x*4){
    const int row0 = tile*16;
    f32x4 acc[3];
    #pragma unroll
    for(int ct = 0; ct < 3; ct++) acc[ct] = (f32x4){0.f,0.f,0.f,0.f};
    #pragma unroll
    for(int kb = 0; kb < 4; kb++){
      short8 a = *reinterpret_cast<const short8*>(h + (size_t)(row0 + r_in)*HID + kb*32 + kg*8);
      #pragma unroll
      for(int ct = 0; ct < 3; ct++){
        short8 bb = *reinterpret_cast<const short8*>(&wlds[ct][kb][lane][0]);
        acc[ct] = __builtin_amdgcn_mfma_f32_16x16x32_bf16(a, bb, acc[ct], 0, 0, 0);
      }
    }
    #pragma unroll
    for(int i = 0; i < 4; i++){
      float v0 = acc[0][i] + bias_s[r_in];
      float v1 = acc[1][i] + bias_s[16 + r_in];
      float v2 = acc[2][i] + bias_s[32 + r_in];
      float m = fmaxf(fmaxf(v0, v1), v2);
      #pragma unroll
      for(int o = 8; o > 0; o >>= 1) m = fmaxf(m, __shfl_xor(m, o));
      float s = expf(v0 - m) + expf(v1 - m) + expf(v2 - m);
      #pragma unroll
      for(int o = 8; o > 0; o >>= 1) s += __shfl_xor(s, o);
      const float ls = m + logf(s);
      const int row = row0 + kg*4 + i;
      float* op = out + (size_t)row*NCLS;
      op[r_in] = v0 - ls;
      op[16 + r_in] = v1 - ls;
      if(r_in < 8) op[32 + r_in] = v2 - ls;
    }
  }
}

extern "C" void kernel_launch(void* const* d_in, const int* in_sizes, int n_in,
                              void* d_out, int out_size, void* d_ws, size_t ws_size,
                              hipStream_t stream)
{
  const float* x      = (const float*)d_in[0];
  const int*   ei     = (const int*)  d_in[1];
  const float* W_pre  = (const float*)d_in[2];
  const float* b_pre  = (const float*)d_in[3];
  const float* Wl0    = (const float*)d_in[4];
  const float* bl0    = (const float*)d_in[5];
  const float* Wr0    = (const float*)d_in[6];
  const float* Wl1    = (const float*)d_in[7];
  const float* bl1    = (const float*)d_in[8];
  const float* Wr1    = (const float*)d_in[9];
  const float* W_post = (const float*)d_in[10];
  const float* b_post = (const float*)d_in[11];
  float* out = (float*)d_out;

  const int E = in_sizes[1] / 2;
  const int* src = ei;
  const int* dst = ei + E;

  char* ws = (char*)d_ws;
  size_t off = 0;
  auto alloc = [&](size_t bytes)->void*{
    void* p = ws + off;
    off += (bytes + 255) & ~(size_t)255;
    return p;
  };
  unsigned short* hA = (unsigned short*)alloc((size_t)N_NODES*HID*2);
  unsigned short* hB = (unsigned short*)alloc((size_t)N_NODES*HID*2);
  unsigned short* hM = (unsigned short*)alloc((size_t)N_NODES*HID*2);
  int* counts   = (int*)alloc((size_t)N_NODES*4);
  int* offs     = (int*)alloc((size_t)N_NODES*4);
  int* cursor   = (int*)alloc((size_t)N_NODES*4);
  int* esrc     = (int*)alloc((size_t)E*4);
  int* partials = (int*)alloc(1024);

  // ---- CSR build (XCD-colored atomics/writes; NT streaming reads) ----
  k_zero<<<(N_NODES+255)/256, 256, 0, stream>>>(counts, N_NODES);
  k_count<<<2048, 256, 0, stream>>>(dst, counts, E);
  const int nb = (N_NODES + SCAN_BLK - 1) / SCAN_BLK;       // 196
  k_scanA<<<nb, SCAN_BLK, 0, stream>>>(counts, offs, partials, N_NODES);
  k_scanB<<<1, 256, 0, stream>>>(partials, nb);
  k_scanC<<<nb, SCAN_BLK, 0, stream>>>(offs, partials, cursor, N_NODES);
  k_scatter<<<2048, 256, 0, stream>>>(src, dst, cursor, esrc, E);

  // ---- pre linear (512x256thr = 2 blocks/CU, pipelined) ----
  k_gemm_pre<<<512, 256, 0, stream>>>(x, W_pre, b_pre, hA);

  // ---- SAGE layer 0 ----
  k_aggregate<<<N_NODES/4, 256, 0, stream>>>(hA, offs, counts, esrc, hM);
  k_gemm_sage<<<512, 256, 0, stream>>>(hM, hA, Wl0, bl0, Wr0, hB);

  // ---- SAGE layer 1 ----
  k_aggregate<<<N_NODES/4, 256, 0, stream>>>(hB, offs, counts, esrc, hM);
  k_gemm_sage<<<512, 256, 0, stream>>>(hM, hB, Wl1, bl1, Wr1, hA);

  // ---- post linear + log_softmax (MFMA) ----
  k_post<<<1563, 256, 0, stream>>>(hA, W_post, b_post, out);
}

// Round 8
// 456.601 us; speedup vs baseline: 1.0420x; 1.0420x over previous
//
#include <hip/hip_runtime.h>
#include <hip/hip_bf16.h>
#include <math.h>

#define N_NODES 100000
#define IN_F 256
#define HID 128
#define NCLS 40
#define CH 2048          // partition chunks
#define CSZ 832          // edges per chunk (64-aligned, CH*CSZ >= E)

typedef __attribute__((ext_vector_type(8))) short short8;
typedef __attribute__((ext_vector_type(4))) float f32x4;

__device__ __forceinline__ short f2bf(float f){
  union { float f; unsigned u; } x; x.f = f;
  unsigned r = (x.u + 0x7fffu + ((x.u >> 16) & 1u)) >> 16;
  return (short)r;
}
__device__ __forceinline__ float bf2f(unsigned short u){
  union { unsigned u; float f; } x; x.u = ((unsigned)u) << 16;
  return x.f;
}

// ---------------- CSR build: deterministic 8-way partition ----------------
__global__ void k_zero(int* p, int n){
  int i = blockIdx.x*blockDim.x + threadIdx.x;
  if(i < n) p[i] = 0;
}

// One wave per chunk: count this chunk's edges per color (no atomics).
__global__ __launch_bounds__(256) void k_pcnt(const int* __restrict__ dst, int e,
                                              int* __restrict__ cnt){
  const int w = blockIdx.x*4 + (threadIdx.x >> 6);
  const int lane = threadIdx.x & 63;
  const int s0 = w*CSZ;
  const int s1 = min(s0 + CSZ, e);
  int c0=0,c1=0,c2=0,c3=0,c4=0,c5=0,c6=0,c7=0;
  for(int i = s0 + lane; i < s1; i += 64){
    const int col = (unsigned)__builtin_nontemporal_load(dst + i) / (N_NODES/8);
    c0 += (col==0); c1 += (col==1); c2 += (col==2); c3 += (col==3);
    c4 += (col==4); c5 += (col==5); c6 += (col==6); c7 += (col==7);
  }
  #pragma unroll
  for(int o = 32; o > 0; o >>= 1){
    c0 += __shfl_xor(c0,o); c1 += __shfl_xor(c1,o); c2 += __shfl_xor(c2,o); c3 += __shfl_xor(c3,o);
    c4 += __shfl_xor(c4,o); c5 += __shfl_xor(c5,o); c6 += __shfl_xor(c6,o); c7 += __shfl_xor(c7,o);
  }
  int outv = c0;
  if(lane==1) outv=c1; if(lane==2) outv=c2; if(lane==3) outv=c3;
  if(lane==4) outv=c4; if(lane==5) outv=c5; if(lane==6) outv=c6; if(lane==7) outv=c7;
  if(lane < 8) cnt[lane*CH + w] = outv;   // color-major layout
}

// Exclusive scan of the 8*CH count matrix (color-major) -> per-(color,chunk) base.
__global__ __launch_bounds__(1024) void k_pscan(const int* __restrict__ cnt,
                                                int* __restrict__ base){
  __shared__ int s[1024];
  const int t = threadIdx.x;
  int v[16]; int sum = 0;
  #pragma unroll
  for(int j = 0; j < 16; j++){ v[j] = cnt[t*16 + j]; int x = sum; sum += v[j]; v[j] = x; }
  s[t] = sum; __syncthreads();
  for(int d = 1; d < 1024; d <<= 1){
    int add = (t >= d) ? s[t-d] : 0;
    __syncthreads();
    s[t] += add;
    __syncthreads();
  }
  const int bofs = (t > 0) ? s[t-1] : 0;
  #pragma unroll
  for(int j = 0; j < 16; j++) base[t*16 + j] = bofs + v[j];
  if(t == 1023) base[8*CH] = s[1023];     // total = E
}

// Same wave mapping: append (dst,src) to per-color contiguous planes via
// ballot ranks. Coalesced writes, zero atomics, deterministic.
__global__ __launch_bounds__(256) void k_pplace(const int* __restrict__ src,
                                                const int* __restrict__ dst, int e,
                                                const int* __restrict__ base,
                                                int* __restrict__ pd, int* __restrict__ ps){
  const int w = blockIdx.x*4 + (threadIdx.x >> 6);
  const int lane = threadIdx.x & 63;
  const int s0 = w*CSZ;
  const int s1 = min(s0 + CSZ, e);
  int b[8];
  #pragma unroll
  for(int k = 0; k < 8; k++) b[k] = base[k*CH + w];
  const unsigned long long ltmask = (lane==63) ? ~0ull>>1 : ((1ull<<lane)-1);
  for(int i0 = s0; i0 < s1; i0 += 64){
    const int i = i0 + lane;
    const bool val = i < s1;
    const int d = val ? __builtin_nontemporal_load(dst + i) : -1;
    const int sv = val ? __builtin_nontemporal_load(src + i) : 0;
    const int col = val ? (int)((unsigned)d / (N_NODES/8)) : -1;
    #pragma unroll
    for(int k = 0; k < 8; k++){
      const unsigned long long m = __ballot(col == k);
      if(col == k){
        const int rank = __popcll(m & ltmask);
        pd[b[k] + rank] = d;
        ps[b[k] + rank] = sv;
      }
      b[k] += __popcll(m);
    }
  }
}

#define SCAN_BLK 512
__global__ void k_scanA(const int* __restrict__ counts, int* __restrict__ offs,
                        int* __restrict__ partials, int n){
  __shared__ int s[SCAN_BLK];
  const int t = threadIdx.x;
  const int i = blockIdx.x*SCAN_BLK + t;
  int v = (i < n) ? counts[i] : 0;
  s[t] = v; __syncthreads();
  for(int d = 1; d < SCAN_BLK; d <<= 1){
    int add = (t >= d) ? s[t-d] : 0;
    __syncthreads();
    s[t] += add;
    __syncthreads();
  }
  if(i < n) offs[i] = s[t] - v;
  if(t == SCAN_BLK-1) partials[blockIdx.x] = s[t];
}

__global__ void k_scanB(int* partials, int n){
  __shared__ int s[256];
  const int t = threadIdx.x;
  int v = (t < n) ? partials[t] : 0;
  s[t] = v; __syncthreads();
  for(int d = 1; d < 256; d <<= 1){
    int add = (t >= d) ? s[t-d] : 0;
    __syncthreads();
    s[t] += add;
    __syncthreads();
  }
  if(t < n) partials[t] = s[t] - v;
}

__global__ void k_scanC(int* __restrict__ offs, const int* __restrict__ partials,
                        int* __restrict__ cursor, int n){
  int i = blockIdx.x*blockDim.x + threadIdx.x;
  if(i < n){
    int v = offs[i] + partials[blockIdx.x];
    offs[i] = v;
    cursor[i] = v;
  }
}

// Colored count from the contiguous color partition (reads 1/8 each).
__global__ __launch_bounds__(256) void k_count2(const int* __restrict__ pd,
                                                const int* __restrict__ base,
                                                int* __restrict__ counts){
  const int color = blockIdx.x & 7;
  const int c0 = base[color*CH], c1 = base[(color+1)*CH];
  const int stride = (gridDim.x >> 3) * 256;
  for(int i = c0 + (blockIdx.x >> 3)*256 + threadIdx.x; i < c1; i += stride)
    atomicAdd(&counts[__builtin_nontemporal_load(pd + i)], 1);
}

// Colored scatter from the contiguous color partition.
__global__ __launch_bounds__(256) void k_scatter2(const int* __restrict__ pd,
                                                  const int* __restrict__ ps,
                                                  const int* __restrict__ base,
                                                  int* __restrict__ cursor,
                                                  int* __restrict__ esrc){
  const int color = blockIdx.x & 7;
  const int c0 = base[color*CH], c1 = base[(color+1)*CH];
  const int stride = (gridDim.x >> 3) * 256;
  for(int i = c0 + (blockIdx.x >> 3)*256 + threadIdx.x; i < c1; i += stride){
    const int d = __builtin_nontemporal_load(pd + i);
    const int s = __builtin_nontemporal_load(ps + i);
    const int pos = atomicAdd(&cursor[d], 1);
    esrc[pos] = s;
  }
}

// ---------------- pre GEMM: h0 = x @ W_pre + b_pre  (f32 in, bf16 out) ----------------
// Proven round-5 config: 4 waves, grid 512, full-tile register prefetch, in-order.
__global__ __launch_bounds__(256) void k_gemm_pre(
    const float* __restrict__ x, const float* __restrict__ W,
    const float* __restrict__ b, unsigned short* __restrict__ out)
{
  __shared__ short wlds[8][8][64][8];   // [ct][kb][lane][j] : B-frag layout, 64 KiB
  const int t = threadIdx.x;
  for(int idx = t; idx < 8*8*64; idx += 256){
    const int ct = idx >> 9, kb = (idx >> 6) & 7, l = idx & 63;
    const int col = ct*16 + (l & 15);
    const int kbase = kb*32 + (l >> 4)*8;
    short8 v;
    #pragma unroll
    for(int j = 0; j < 8; j++) v[j] = f2bf(W[(size_t)(kbase+j)*HID + col]);
    *reinterpret_cast<short8*>(&wlds[ct][kb][l][0]) = v;
  }
  __syncthreads();
  const int wave = t >> 6, lane = t & 63;
  const int r_in = lane & 15, kg = lane >> 4;
  for(int tile = blockIdx.x*4 + wave; tile < N_NODES/16; tile += gridDim.x*4){
    const int row0 = tile*16;
    const float* xp = x + (size_t)(row0 + r_in)*IN_F + kg*8;
    float4 xa[8], xb[8];
    #pragma unroll
    for(int kb = 0; kb < 8; kb++){
      xa[kb] = *reinterpret_cast<const float4*>(xp + kb*32);
      xb[kb] = *reinterpret_cast<const float4*>(xp + kb*32 + 4);
    }
    f32x4 acc[8];
    #pragma unroll
    for(int ct = 0; ct < 8; ct++) acc[ct] = (f32x4){0.f,0.f,0.f,0.f};
    #pragma unroll
    for(int kb = 0; kb < 8; kb++){
      short8 a;
      a[0]=f2bf(xa[kb].x); a[1]=f2bf(xa[kb].y); a[2]=f2bf(xa[kb].z); a[3]=f2bf(xa[kb].w);
      a[4]=f2bf(xb[kb].x); a[5]=f2bf(xb[kb].y); a[6]=f2bf(xb[kb].z); a[7]=f2bf(xb[kb].w);
      #pragma unroll
      for(int ct = 0; ct < 8; ct++){
        short8 bb = *reinterpret_cast<const short8*>(&wlds[ct][kb][lane][0]);
        acc[ct] = __builtin_amdgcn_mfma_f32_16x16x32_bf16(a, bb, acc[ct], 0, 0, 0);
      }
    }
    #pragma unroll
    for(int ct = 0; ct < 8; ct++){
      const int col = ct*16 + r_in;
      const float bias = b[col];
      #pragma unroll
      for(int i = 0; i < 4; i++){
        const int row = row0 + kg*4 + i;
        out[(size_t)row*HID + col] = (unsigned short)f2bf(acc[ct][i] + bias);
      }
    }
  }
}

// ------- sage GEMM: out = relu(mean @ Wl + bl + h @ Wr)  (bf16 in/out) -------
// Proven round-4 config: 4 waves, grid 1563, in-order.
__global__ __launch_bounds__(256) void k_gemm_sage(
    const unsigned short* __restrict__ mean, const unsigned short* __restrict__ h,
    const float* __restrict__ Wl, const float* __restrict__ bl,
    const float* __restrict__ Wr, unsigned short* __restrict__ out)
{
  __shared__ short wlds[8][8][64][8];   // kb 0..3 -> Wl, 4..7 -> Wr
  const int t = threadIdx.x;
  for(int idx = t; idx < 8*8*64; idx += 256){
    const int ct = idx >> 9, kb = (idx >> 6) & 7, l = idx & 63;
    const float* Wsrc = (kb < 4) ? Wl : Wr;
    const int col = ct*16 + (l & 15);
    const int kbase = (kb & 3)*32 + (l >> 4)*8;
    short8 v;
    #pragma unroll
    for(int j = 0; j < 8; j++) v[j] = f2bf(Wsrc[(size_t)(kbase+j)*HID + col]);
    *reinterpret_cast<short8*>(&wlds[ct][kb][l][0]) = v;
  }
  __syncthreads();
  const int wave = t >> 6, lane = t & 63;
  const int r_in = lane & 15, kg = lane >> 4;
  for(int tile = blockIdx.x*4 + wave; tile < N_NODES/16; tile += gridDim.x*4){
    const int row0 = tile*16;
    f32x4 acc[8];
    #pragma unroll
    for(int ct = 0; ct < 8; ct++) acc[ct] = (f32x4){0.f,0.f,0.f,0.f};
    #pragma unroll
    for(int kb = 0; kb < 8; kb++){
      const unsigned short* in = (kb < 4) ? mean : h;
      const int koff = (kb & 3)*32 + kg*8;
      short8 a = *reinterpret_cast<const short8*>(in + (size_t)(row0 + r_in)*HID + koff);
      #pragma unroll
      for(int ct = 0; ct < 8; ct++){
        short8 bb = *reinterpret_cast<const short8*>(&wlds[ct][kb][lane][0]);
        acc[ct] = __builtin_amdgcn_mfma_f32_16x16x32_bf16(a, bb, acc[ct], 0, 0, 0);
      }
    }
    #pragma unroll
    for(int ct = 0; ct < 8; ct++){
      const int col = ct*16 + r_in;
      const float bias = bl[col];
      #pragma unroll
      for(int i = 0; i < 4; i++){
        const int row = row0 + kg*4 + i;
        float v = fmaxf(acc[ct][i] + bias, 0.f);
        out[(size_t)row*HID + col] = (unsigned short)f2bf(v);
      }
    }
  }
}

// ---------------- CSR mean aggregation (bf16 h -> bf16 mean) ----------------
__global__ __launch_bounds__(256) void k_aggregate(
    const unsigned short* __restrict__ h, const int* __restrict__ offs,
    const int* __restrict__ counts, const int* __restrict__ esrc,
    unsigned short* __restrict__ mean)
{
  const int node = blockIdx.x*4 + (threadIdx.x >> 6);
  const int lane = threadIdx.x & 63;
  if(node >= N_NODES) return;
  const int beg = offs[node];
  const int deg = counts[node];
  const unsigned* hp = (const unsigned*)h;
  float a0 = 0.f, a1 = 0.f;
  for(int base = 0; base < deg; base += 64){
    const int rem = deg - base;
    const int cnt = rem < 64 ? rem : 64;
    const int myi = (lane < cnt) ? esrc[beg + base + lane] : 0;   // coalesced
    int e = 0;
    for(; e + 8 <= cnt; e += 8){
      unsigned v[8];
      #pragma unroll
      for(int u = 0; u < 8; u++){
        const int s = __builtin_amdgcn_readlane(myi, e + u);
        v[u] = hp[(size_t)s*64 + lane];
      }
      #pragma unroll
      for(int u = 0; u < 8; u++){
        a0 += bf2f((unsigned short)(v[u] & 0xffffu));
        a1 += bf2f((unsigned short)(v[u] >> 16));
      }
    }
    for(; e < cnt; e++){
      const int s = __builtin_amdgcn_readlane(myi, e);
      const unsigned vv = hp[(size_t)s*64 + lane];
      a0 += bf2f((unsigned short)(vv & 0xffffu));
      a1 += bf2f((unsigned short)(vv >> 16));
    }
  }
  const float inv = (deg > 0) ? (1.0f/(float)deg) : 0.f;
  a0 *= inv; a1 *= inv;
  unsigned o = ((unsigned)(unsigned short)f2bf(a1) << 16) | (unsigned)(unsigned short)f2bf(a0);
  ((unsigned*)mean)[(size_t)node*64 + lane] = o;
}

// ---------------- post: log_softmax(h @ W_post + b_post), MFMA ----------------
__global__ __launch_bounds__(256) void k_post(
    const unsigned short* __restrict__ h, const float* __restrict__ W,
    const float* __restrict__ b, float* __restrict__ out)
{
  __shared__ short wlds[3][4][64][8];   // [ct][kb][lane][j], 12 KiB
  __shared__ float bias_s[48];
  const int t = threadIdx.x;
  for(int idx = t; idx < 3*4*64; idx += 256){
    const int ct = idx >> 8, kb = (idx >> 6) & 3, l = idx & 63;
    const int col = ct*16 + (l & 15);
    const int kbase = kb*32 + (l >> 4)*8;
    short8 v;
    #pragma unroll
    for(int j = 0; j < 8; j++)
      v[j] = (col < NCLS) ? f2bf(W[(size_t)(kbase+j)*NCLS + col]) : (short)0;
    *reinterpret_cast<short8*>(&wlds[ct][kb][l][0]) = v;
  }
  if(t < 48) bias_s[t] = (t < NCLS) ? b[t] : -1e30f;
  __syncthreads();
  const int wave = t >> 6, lane = t & 63;
  const int r_in = lane & 15, kg = lane >> 4;
  for(int tile = blockIdx.x*4 + wave; tile < N_NODES/16; tile += gridDim.x*4){
    const int row0 = tile*16;
    f32x4 acc[3];
    #pragma unroll
    for(int ct = 0; ct < 3; ct++) acc[ct] = (f32x4){0.f,0.f,0.f,0.f};
    #pragma unroll
    for(int kb = 0; kb < 4; kb++){
      short8 a = *reinterpret_cast<const short8*>(h + (size_t)(row0 + r_in)*HID + kb*32 + kg*8);
      #pragma unroll
      for(int ct = 0; ct < 3; ct++){
        short8 bb = *reinterpret_cast<const short8*>(&wlds[ct][kb][lane][0]);
        acc[ct] = __builtin_amdgcn_mfma_f32_16x16x32_bf16(a, bb, acc[ct], 0, 0, 0);
      }
    }
    #pragma unroll
    for(int i = 0; i < 4; i++){
      float v0 = acc[0][i] + bias_s[r_in];
      float v1 = acc[1][i] + bias_s[16 + r_in];
      float v2 = acc[2][i] + bias_s[32 + r_in];
      float m = fmaxf(fmaxf(v0, v1), v2);
      #pragma unroll
      for(int o = 8; o > 0; o >>= 1) m = fmaxf(m, __shfl_xor(m, o));
      float s = expf(v0 - m) + expf(v1 - m) + expf(v2 - m);
      #pragma unroll
      for(int o = 8; o > 0; o >>= 1) s += __shfl_xor(s, o);
      const float ls = m + logf(s);
      const int row = row0 + kg*4 + i;
      float* op = out + (size_t)row*NCLS;
      op[r_in] = v0 - ls;
      op[16 + r_in] = v1 - ls;
      if(r_in < 8) op[32 + r_in] = v2 - ls;
    }
  }
}

extern "C" void kernel_launch(void* const* d_in, const int* in_sizes, int n_in,
                              void* d_out, int out_size, void* d_ws, size_t ws_size,
                              hipStream_t stream)
{
  const float* x      = (const float*)d_in[0];
  const int*   ei     = (const int*)  d_in[1];
  const float* W_pre  = (const float*)d_in[2];
  const float* b_pre  = (const float*)d_in[3];
  const float* Wl0    = (const float*)d_in[4];
  const float* bl0    = (const float*)d_in[5];
  const float* Wr0    = (const float*)d_in[6];
  const float* Wl1    = (const float*)d_in[7];
  const float* bl1    = (const float*)d_in[8];
  const float* Wr1    = (const float*)d_in[9];
  const float* W_post = (const float*)d_in[10];
  const float* b_post = (const float*)d_in[11];
  float* out = (float*)d_out;

  const int E = in_sizes[1] / 2;
  const int* src = ei;
  const int* dst = ei + E;

  char* ws = (char*)d_ws;
  size_t off = 0;
  auto alloc = [&](size_t bytes)->void*{
    void* p = ws + off;
    off += (bytes + 255) & ~(size_t)255;
    return p;
  };
  unsigned short* hA = (unsigned short*)alloc((size_t)N_NODES*HID*2);
  unsigned short* hB = (unsigned short*)alloc((size_t)N_NODES*HID*2);
  unsigned short* hM = (unsigned short*)alloc((size_t)N_NODES*HID*2);
  int* counts   = (int*)alloc((size_t)N_NODES*4);
  int* offs     = (int*)alloc((size_t)N_NODES*4);
  int* cursor   = (int*)alloc((size_t)N_NODES*4);
  int* esrc     = (int*)alloc((size_t)E*4);
  int* partials = (int*)alloc(1024);

  // Partition scratch aliased into buffers that are only written AFTER the
  // CSR build completes (hM: first written by layer-0 aggregate; hB: first
  // written by layer-0 sage GEMM).
  int* pd   = (int*)hM;            // CH*CSZ ints (6.8 MB)
  int* ps   = pd + CH*CSZ;         // CH*CSZ ints (6.8 MB)  -> 13.6 MB < 25.6 MB
  int* cnt  = (int*)hB;            // 8*CH ints
  int* base = cnt + 8*CH;          // 8*CH+1 ints           -> 131 KB < 25.6 MB

  // ---- CSR build: deterministic partition -> colored count/scatter ----
  k_zero<<<(N_NODES+255)/256, 256, 0, stream>>>(counts, N_NODES);
  k_pcnt<<<CH/4, 256, 0, stream>>>(dst, E, cnt);
  k_pscan<<<1, 1024, 0, stream>>>(cnt, base);
  k_pplace<<<CH/4, 256, 0, stream>>>(src, dst, E, base, pd, ps);
  k_count2<<<2048, 256, 0, stream>>>(pd, base, counts);
  const int nb = (N_NODES + SCAN_BLK - 1) / SCAN_BLK;       // 196
  k_scanA<<<nb, SCAN_BLK, 0, stream>>>(counts, offs, partials, N_NODES);
  k_scanB<<<1, 256, 0, stream>>>(partials, nb);
  k_scanC<<<nb, SCAN_BLK, 0, stream>>>(offs, partials, cursor, N_NODES);
  k_scatter2<<<2048, 256, 0, stream>>>(pd, ps, base, cursor, esrc);

  // ---- pre linear (proven: 512 blocks x 4 waves, register tile prefetch) ----
  k_gemm_pre<<<512, 256, 0, stream>>>(x, W_pre, b_pre, hA);

  // ---- SAGE layer 0 ----
  k_aggregate<<<N_NODES/4, 256, 0, stream>>>(hA, offs, counts, esrc, hM);
  k_gemm_sage<<<1563, 256, 0, stream>>>(hM, hA, Wl0, bl0, Wr0, hB);

  // ---- SAGE layer 1 ----
  k_aggregate<<<N_NODES/4, 256, 0, stream>>>(hB, offs, counts, esrc, hM);
  k_gemm_sage<<<1563, 256, 0, stream>>>(hM, hB, Wl1, bl1, Wr1, hA);

  // ---- post linear + log_softmax (MFMA) ----
  k_post<<<1563, 256, 0, stream>>>(hA, W_post, b_post, out);
}